// Round 9
// baseline (1318.475 us; speedup 1.0000x reference)
//
#include <hip/hip_runtime.h>
#include <math.h>

// ---------------------------------------------------------------------------
// LocalModel_76527727280750: 6-layer transformer w/ unfold-window attention.
// B=2 S=2048 E=512 H=8 DH=64 W=5 SK=2044 HID=2048 OUT=6 L=6, fp32 in/out.
//
// R16: (a) GEMM BM=64 tile variant for tail-clean grids: fc2 128->256
// blocks (was HALF-GPU-idle), QKV 384->768 (3 clean waves); fc1 stays
// BM=128 (512 = 2.0 waves already).  (b) flash half-Q-hoist: the d0=0
// half of the Q fragments (10 b128 = 40 VGPR) is loop-invariant across
// all 16 t-iterations -- hoisted to registers after Q staging, cutting
// QK^T LDS reads 23% while staying under the 128-VGPR cliff (~104).
// GEMM dbuf gload_lds staging (R15-verified) unchanged.
// ---------------------------------------------------------------------------

namespace {
constexpr int kB   = 2;
constexpr int kS   = 2048;
constexpr int kE   = 512;
constexpr int kH   = 8;
constexpr int kDH  = 64;
constexpr int kSK  = 2044;   // S - W + 1
constexpr int kHID = 2048;
constexpr int kL   = 6;
constexpr float kScaleL2 = 0.125f * 1.44269504088896f;  // DH^-0.5 * log2(e)
constexpr int kTok = kB * kS;         // 4096 rows
constexpr int kNX  = kTok * kE;       // 2,097,152 floats
constexpr int kQKV = 3 * kE;          // 1536 fused row stride
constexpr int kSQ  = 72;              // Qs/Ks LDS row stride (f16), 144 B
constexpr int kSV  = 136;             // Vt LDS row stride (f16), 272 B
}

using f16x8   = __attribute__((ext_vector_type(8))) _Float16;
using floatx4 = __attribute__((ext_vector_type(4))) float;
using uint2v  = __attribute__((ext_vector_type(2))) unsigned int;
using uint4v  = __attribute__((ext_vector_type(4))) unsigned int;

static __device__ __forceinline__ unsigned short f2h(float f) {
  return __builtin_bit_cast(unsigned short, (_Float16)f);
}
static __device__ __forceinline__ float h2f(unsigned short u) {
  return (float)__builtin_bit_cast(_Float16, u);
}
static __device__ __forceinline__ unsigned int pk2h(float a, float b) {
  return __builtin_bit_cast(unsigned int, __builtin_amdgcn_cvt_pkrtz(a, b));
}
// direct global->LDS copy, 16 B per lane; lds base must be wave-uniform,
// HW writes at base + lane*16.
static __device__ __forceinline__ void gload_lds16(const unsigned short* g,
                                                   unsigned short* l) {
  __builtin_amdgcn_global_load_lds(
      (const __attribute__((address_space(1))) void*)g,
      (__attribute__((address_space(3))) void*)l, 16, 0, 0);
}
// partner value across the lane^16 split (rows 0<->1, 2<->3), VALU-only.
// even-row lanes: partner lands in new_vsrc (r[1]); odd-row: new_vdst (r[0]).
static __device__ __forceinline__ float red16(float x, bool hi) {
  const unsigned u = __builtin_bit_cast(unsigned, x);
  const uint2v r = __builtin_amdgcn_permlane16_swap(u, u, false, false);
  return __builtin_bit_cast(float, hi ? r[0] : r[1]);
}
// partner value across the lane^32 split (halves), VALU-only
static __device__ __forceinline__ float red32(float x, bool hi) {
  const unsigned u = __builtin_bit_cast(unsigned, x);
  const uint2v r = __builtin_amdgcn_permlane32_swap(u, u, false, false);
  return __builtin_bit_cast(float, hi ? r[0] : r[1]);
}

// ---------------- embedding + sinusoidal positional encoding (f16 out) ------
__global__ __launch_bounds__(256) void embed_kernel(const int* __restrict__ idx,
        const float* __restrict__ emb, unsigned short* __restrict__ X) {
  const int bs  = blockIdx.x;            // b*S + s
  const int s   = bs & (kS - 1);
  const int tok = idx[bs];
  const int t   = threadIdx.x;
#pragma unroll
  for (int r = 0; r < 2; ++r) {
    const int e = t + 256 * r;
    const int i = e >> 1;
    const float dv  = __expf((float)(2 * i) * (-9.210340371976184f / (float)kE));
    const float ang = (float)s * dv;
    const float pe  = (e & 1) ? cosf(ang) : sinf(ang);   // libm: accurate arg reduction
    X[bs * kE + e] = f2h(emb[tok * kE + e] + pe);
  }
}

// ---------------- weight transpose-cast: fp32 [K][N] -> f16 [N][K] ----------
__global__ __launch_bounds__(256) void tcast_kernel(const float* __restrict__ src,
        unsigned short* __restrict__ dst, int K, int N) {
  __shared__ float t[32][33];
  const int tid = threadIdx.x;
  const int tx = tid & 31, ty = tid >> 5;          // 32 x 8
  const int n0 = blockIdx.x * 32, k0 = blockIdx.y * 32;
#pragma unroll
  for (int p = 0; p < 4; ++p)
    t[ty + 8 * p][tx] = src[(size_t)(k0 + ty + 8 * p) * N + n0 + tx];
  __syncthreads();
#pragma unroll
  for (int p = 0; p < 4; ++p)
    dst[(size_t)(n0 + ty + 8 * p) * K + k0 + tx] = f2h(t[tx][ty + 8 * p]);
}

__global__ __launch_bounds__(256) void qkvb_kernel(const float* __restrict__ qb,
        const float* __restrict__ kb, const float* __restrict__ vb,
        float* __restrict__ dst) {
  const int i = blockIdx.x * 256 + threadIdx.x;    // grid 6 -> 1536
  dst[i] = (i < 512) ? qb[i] : ((i < 1024) ? kb[i - 512] : vb[i - 1024]);
}

// ---------------- f16 MFMA GEMM: C = act(A@B + bias [+ R]) ------------------
// A f16 [M,K], Bt f16 [N,K] (pre-transposed), C f16, R f16 residual.
// Tile BM x 128, 4 waves, K-step 32, double-buffered gload_lds staging
// (zero VGPR cost; ONE barrier per K-step, loads overlap the MFMA phase).
// BM=128: waves 2x2 quadrants of 64x64, acc[4][4].
// BM=64:  waves 1x4 strips of 64x32,  acc[4][2]  (tail-clean small grids).
template <int BM, int RELU, int RES>
__global__ __launch_bounds__(256) void mfma_gemm(const unsigned short* __restrict__ A,
        const unsigned short* __restrict__ Bt, const float* __restrict__ bias,
        const unsigned short* __restrict__ Rm, unsigned short* __restrict__ C,
        int M, int N, int K) {
  constexpr int NT = (BM == 128) ? 4 : 2;          // n-frags per wave
  constexpr int AP = BM / 64;                      // A staging passes
  __shared__ __align__(16) unsigned short As[2][BM * 32];
  __shared__ __align__(16) unsigned short Bs[2][128 * 32];
  const int tid = threadIdx.x;
  const int m0 = blockIdx.y * BM, n0 = blockIdx.x * 128;
  const int wid = tid >> 6, lane = tid & 63;
  const int lm = lane & 15, quad = lane >> 4;
  const int wm = (BM == 128) ? (wid & 1) * 64 : 0;
  const int wn = (BM == 128) ? (wid >> 1) * 64 : wid * 32;
  const int bn = tid >> 2, bk = (tid & 3) * 8;     // staging row / col
  const int wslot = wid * 512;                     // wave-uniform LDS slot
  // prologue: stage K-step 0 into buffer 0
#pragma unroll
  for (int p = 0; p < AP; ++p)
    gload_lds16(&A[(size_t)(m0 + bn + 64 * p) * K + bk], &As[0][p * 2048 + wslot]);
#pragma unroll
  for (int p = 0; p < 2; ++p)
    gload_lds16(&Bt[(size_t)(n0 + bn + 64 * p) * K + bk], &Bs[0][p * 2048 + wslot]);
  __syncthreads();                                 // vmcnt drain -> buf0 ready
  floatx4 acc[4][NT] = {};
  for (int k0 = 0; k0 < K; k0 += 32) {
    const int cur = (k0 >> 5) & 1;
    const int kn = k0 + 32;
    if (kn < K) {                                  // stage next tile (async)
#pragma unroll
      for (int p = 0; p < AP; ++p)
        gload_lds16(&A[(size_t)(m0 + bn + 64 * p) * K + kn + bk],
                    &As[cur ^ 1][p * 2048 + wslot]);
#pragma unroll
      for (int p = 0; p < 2; ++p)
        gload_lds16(&Bt[(size_t)(n0 + bn + 64 * p) * K + kn + bk],
                    &Bs[cur ^ 1][p * 2048 + wslot]);
    }
    f16x8 af[4], bf[NT];
#pragma unroll
    for (int t = 0; t < 4; ++t)
      af[t] = *(const f16x8*)&As[cur][(wm + t * 16 + lm) * 32 + quad * 8];
#pragma unroll
    for (int t = 0; t < NT; ++t)
      bf[t] = *(const f16x8*)&Bs[cur][(wn + t * 16 + lm) * 32 + quad * 8];
#pragma unroll
    for (int mt = 0; mt < 4; ++mt)
#pragma unroll
      for (int nt = 0; nt < NT; ++nt)
        acc[mt][nt] = __builtin_amdgcn_mfma_f32_16x16x32_f16(
            af[mt], bf[nt], acc[mt][nt], 0, 0, 0);
    __syncthreads();   // next buf ready (vmcnt) + all reads of cur done
  }
  // epilogue: D col = lane&15 (n), row = quad*4+reg (m)
#pragma unroll
  for (int mt = 0; mt < 4; ++mt) {
#pragma unroll
    for (int nt = 0; nt < NT; ++nt) {
      const int n = n0 + wn + nt * 16 + lm;
      const float bv = bias[n];
#pragma unroll
      for (int r = 0; r < 4; ++r) {
        const int m = m0 + wm + mt * 16 + quad * 4 + r;
        float o = acc[mt][nt][r] + bv;
        if (RES) o += h2f(Rm[(size_t)m * N + n]);
        if (RELU) o = fmaxf(o, 0.f);
        C[(size_t)m * N + n] = f2h(o);
      }
    }
  }
}

// ---------------- fused window-presum + transpose of V ----------------------
// VsT[(b*H+h)*64 + d][t] = sum_{w<5} V[b][t+w][h*64+d]  (f16, t-dim 2048,
// zero for t >= SK).  fp32 LDS tile stride 65 -> conflict-free col reads.
__global__ __launch_bounds__(256) void vsumt_kernel(const unsigned short* __restrict__ QKVh,
        unsigned short* __restrict__ VsT) {
  const int t0 = blockIdx.x * 64;                  // 32 t-tiles
  const int h = blockIdx.y, b = blockIdx.z;
  const int tid = threadIdx.x;
  __shared__ float Ls[68 * 65];
  for (int id = tid; id < 68 * 8; id += 256) {     // stage 68 rows x 64 d
    const int row = id >> 3, d8 = (id & 7) * 8;
    const int gt = t0 + row;
    float v[8];
    if (gt < kS) {
      const unsigned short* p =
          &QKVh[(size_t)(b * kS + gt) * kQKV + 2 * kE + h * kDH + d8];
      const ushort4 a = *(const ushort4*)p;
      const ushort4 c = *(const ushort4*)(p + 4);
      v[0] = h2f(a.x); v[1] = h2f(a.y); v[2] = h2f(a.z); v[3] = h2f(a.w);
      v[4] = h2f(c.x); v[5] = h2f(c.y); v[6] = h2f(c.z); v[7] = h2f(c.w);
    } else {
#pragma unroll
      for (int j = 0; j < 8; ++j) v[j] = 0.f;
    }
#pragma unroll
    for (int j = 0; j < 8; ++j) Ls[row * 65 + d8 + j] = v[j];
  }
  __syncthreads();
  const int t4 = (tid & 15) * 4;
#pragma unroll
  for (int c = 0; c < 4; ++c) {
    const int d = (tid >> 4) + 16 * c;
    ushort4 o;
    unsigned short* op = (unsigned short*)&o;
#pragma unroll
    for (int j = 0; j < 4; ++j) {
      const int tl = t4 + j;
      float s = Ls[(tl + 0) * 65 + d] + Ls[(tl + 1) * 65 + d]
              + Ls[(tl + 2) * 65 + d] + Ls[(tl + 3) * 65 + d]
              + Ls[(tl + 4) * 65 + d];
      if (t0 + tl >= kSK) s = 0.f;
      op[j] = f2h(s);
    }
    *(ushort4*)&VsT[((size_t)(b * kH + h) * kDH + d) * (size_t)kS + t0 + t4] = o;
  }
}

// ---------------- MFMA flash attention (unfold contraction) -----------------
// Block = 512 thr (8 waves 2x4), (qt of 64 q, h, b), grid 512.
// Wave (wq,wt): q-rows 32wq..+32 x t-strip 32wt..+32 of each 128-wide tile.
// QK^T computed SWAPPED: sac[tf][qf] = mfma(K,Q) -> D row = t (quad*4+r),
// col = q (lm).  d0=0 half of the Q frags hoisted to registers (loop-
// invariant; 10 b128 = 40 VGPR, stays under the 128-reg cliff).
// Softmax reduce over t in-lane + permlane16/32; PV A-frags in registers
// via cvt_pkrtz + permlane; T13 defer-max skips rescale when no growth.
__global__ __launch_bounds__(512) void flash_kernel(const unsigned short* __restrict__ QKVh,
        const unsigned short* __restrict__ VsT, unsigned short* __restrict__ O) {
  const int tid = threadIdx.x;
  const int qt = blockIdx.x, h = blockIdx.y, b = blockIdx.z;
  const int q0 = qt * 64;
  const int wid = tid >> 6, lane = tid & 63;
  const int lm = lane & 15, quad = lane >> 4;
  const bool h16 = (lane & 16) != 0, h32 = (lane & 32) != 0;
  const int wq = wid >> 2, wt = wid & 3;
  const int bh = b * kH + h;

  __shared__ __align__(16) unsigned short Qs[68 * kSQ];    //  9.8 KB
  __shared__ __align__(16) unsigned short Ks[132 * kSQ];   // 19.0 KB
  __shared__ __align__(16) unsigned short Vt[64 * kSV];    // 17.4 KB  [d][t]
  __shared__ float mM[64][4], lM[64][4];

  // Q staging: rows i -> global q0-2+i (zero-pad OOB)
  for (int id = tid; id < 68 * 16; id += 512) {
    const int row = id >> 4, c4 = (id & 15) * 4;
    const int gq = q0 - 2 + row;
    ushort4 v = make_ushort4(0, 0, 0, 0);
    if (gq >= 0 && gq < kS)
      v = *(const ushort4*)&QKVh[(size_t)(b * kS + gq) * kQKV + h * kDH + c4];
    *(ushort4*)&Qs[row * kSQ + c4] = v;
  }

  // register-prefetch staging (fixed per-thread mapping; 512 threads)
  const int prow = tid >> 4;                 // 0..31
  const int pc4 = (tid & 15) * 4, pc8 = (tid & 15) * 8;
  ushort4 kreg[5];
  uint4 vreg[2];
#define PREFETCH(T0)                                                          \
  {                                                                           \
    _Pragma("unroll")                                                         \
    for (int p = 0; p < 5; ++p) {                                             \
      const int row = prow + 32 * p;                                          \
      ushort4 v = make_ushort4(0, 0, 0, 0);                                   \
      if (row < 132) {                                                        \
        const int gk = (T0) + row;                                            \
        if (gk < kS)                                                          \
          v = *(const ushort4*)&QKVh[(size_t)(b * kS + gk) * kQKV + kE +      \
                                     h * kDH + pc4];                          \
      }                                                                       \
      kreg[p] = v;                                                            \
    }                                                                         \
    _Pragma("unroll")                                                         \
    for (int p = 0; p < 2; ++p)                                               \
      vreg[p] = *(const uint4*)&VsT[((size_t)bh * kDH + prow + 32 * p) *      \
                                    (size_t)kS + (T0) + pc8];                 \
  }
  PREFETCH(0)

  // hoist the d0=0 half of the Q fragments (loop-invariant, 10 b128)
  __syncthreads();                           // Q staging visible
  f16x8 qreg[2][5];
#pragma unroll
  for (int w = 0; w < 5; ++w) {
    qreg[0][w] = *(const f16x8*)&Qs[(wq * 32 + lm + w) * kSQ + quad * 8];
    qreg[1][w] = *(const f16x8*)&Qs[(wq * 32 + 16 + lm + w) * kSQ + quad * 8];
  }

  float mrow[2], lrow[2];                    // per qf, q = wq*32+qf*16+lm,
  mrow[0] = mrow[1] = -1e30f;                // replicated across quads
  lrow[0] = lrow[1] = 0.f;
  floatx4 Oacc[2][4] = {};   // [qf][nt2]: row wq*32+qf*16+quad*4+r, col nt2*16+lm
  const int asrc = (lane >> 2) & 12;         // = quad*4 (shfl src base)

  for (int t0 = 0; t0 < kSK; t0 += 128) {          // 16 iterations
    __syncthreads();                                // prev iter LDS reads done
#pragma unroll
    for (int p = 0; p < 5; ++p) {                   // write prefetched K tile
      const int row = prow + 32 * p;
      if (row < 132) *(ushort4*)&Ks[row * kSQ + pc4] = kreg[p];
    }
#pragma unroll
    for (int p = 0; p < 2; ++p)                     // write prefetched Vt tile
      *(uint4*)&Vt[(prow + 32 * p) * kSV + pc8] = vreg[p];
    __syncthreads();
    const int tn = t0 + 128;
    if (tn < kSK) PREFETCH(tn)                      // next tile in flight

    // QK^T swapped: 10 k-steps (w = kk>>1, d0 = (kk&1)*32)
    // sac[tf][qf]: row = t (wt*32+tf*16+quad*4+r), col = q (wq*32+qf*16+lm)
    floatx4 sac[2][2] = {};
    __builtin_amdgcn_s_setprio(1);
#pragma unroll
    for (int kk = 0; kk < 10; ++kk) {
      const int w = kk >> 1, d0 = (kk & 1) * 32;
      const f16x8 kf0 = *(const f16x8*)&Ks[(wt * 32 + lm + w) * kSQ + d0 + quad * 8];
      const f16x8 kf1 = *(const f16x8*)&Ks[(wt * 32 + 16 + lm + w) * kSQ + d0 + quad * 8];
      f16x8 qf0, qf1;
      if ((kk & 1) == 0) {                          // d0=0: from registers
        qf0 = qreg[0][w];
        qf1 = qreg[1][w];
      } else {                                      // d0=32: from LDS
        qf0 = *(const f16x8*)&Qs[(wq * 32 + lm + w) * kSQ + 32 + quad * 8];
        qf1 = *(const f16x8*)&Qs[(wq * 32 + 16 + lm + w) * kSQ + 32 + quad * 8];
      }
      sac[0][0] = __builtin_amdgcn_mfma_f32_16x16x32_f16(kf0, qf0, sac[0][0], 0, 0, 0);
      sac[0][1] = __builtin_amdgcn_mfma_f32_16x16x32_f16(kf0, qf1, sac[0][1], 0, 0, 0);
      sac[1][0] = __builtin_amdgcn_mfma_f32_16x16x32_f16(kf1, qf0, sac[1][0], 0, 0, 0);
      sac[1][1] = __builtin_amdgcn_mfma_f32_16x16x32_f16(kf1, qf1, sac[1][1], 0, 0, 0);
    }
    __builtin_amdgcn_s_setprio(0);

    // OOB t masking: wave-uniform branch, taken by one wave on the last tile
    if (t0 + wt * 32 + 32 > kSK) {
#pragma unroll
      for (int tf = 0; tf < 2; ++tf)
#pragma unroll
        for (int r = 0; r < 4; ++r) {
          const int tg = t0 + wt * 32 + tf * 16 + quad * 4 + r;
          if (tg >= kSK) { sac[tf][0][r] = -1e30f; sac[tf][1][r] = -1e30f; }
        }
    }

    // softmax: reduce over t = in-lane (2 tf x 4 r) + permlane 16/32 swaps
    float alpha_q[2];
    int skip_q[2];
    f16x8 pfrag[2];
#pragma unroll
    for (int qf = 0; qf < 2; ++qf) {
      float mx = fmaxf(
          fmaxf(fmaxf(sac[0][qf][0], sac[0][qf][1]), fmaxf(sac[0][qf][2], sac[0][qf][3])),
          fmaxf(fmaxf(sac[1][qf][0], sac[1][qf][1]), fmaxf(sac[1][qf][2], sac[1][qf][3])));
      mx = fmaxf(mx, red16(mx, h16));
      mx = fmaxf(mx, red32(mx, h32));
      const float mxs = mx * kScaleL2;
      // T13 defer-max: keep stale m when growth <= 8 (P bounded by 2^8)
      const int skip = __all(mxs <= mrow[qf] + 8.f);
      float mnew, al;
      if (skip) { mnew = mrow[qf]; al = 1.f; }
      else      { mnew = fmaxf(mrow[qf], mxs); al = exp2f(mrow[qf] - mnew); }
      float e[2][4];
#pragma unroll
      for (int tf = 0; tf < 2; ++tf)
#pragma unroll
        for (int r = 0; r < 4; ++r)
          e[tf][r] = exp2f(fmaf(sac[tf][qf][r], kScaleL2, -mnew));
      float ps = ((e[0][0] + e[0][1]) + (e[0][2] + e[0][3]))
               + ((e[1][0] + e[1][1]) + (e[1][2] + e[1][3]));
      ps += red16(ps, h16);
      ps += red32(ps, h32);
      lrow[qf] = lrow[qf] * al + ps;
      mrow[qf] = mnew;
      alpha_q[qf] = al;
      skip_q[qf] = skip;
      // build PV A-frag in registers: words w[tf][p] = (e[tf][2p], e[tf][2p+1])
      // dest dword dw covers t = quad*8 + 2dw + {0,1}
      const unsigned w00 = pk2h(e[0][0], e[0][1]);
      const unsigned w01 = pk2h(e[0][2], e[0][3]);
      const unsigned w10 = pk2h(e[1][0], e[1][1]);
      const unsigned w11 = pk2h(e[1][2], e[1][3]);
      // X=[w00r0,w00r1,w10r0,w10r1], Y=[w00r2,w00r3,w10r2,w10r3] (by 16-row)
      const uint2v sA = __builtin_amdgcn_permlane32_swap(w00, w10, false, false);
      const uint2v dA = __builtin_amdgcn_permlane16_swap(sA[0], sA[1], false, false); // {dw0, dw2}
      const uint2v sB = __builtin_amdgcn_permlane32_swap(w01, w11, false, false);
      const uint2v dB = __builtin_amdgcn_permlane16_swap(sB[0], sB[1], false, false); // {dw1, dw3}
      uint4v fr;
      fr[0] = dA[0]; fr[1] = dB[0]; fr[2] = dA[1]; fr[3] = dB[1];
      pfrag[qf] = __builtin_bit_cast(f16x8, fr);
    }
    // rescale Oacc only when some max actually grew (wave-uniform branch)
    if (!(skip_q[0] && skip_q[1])) {
      float alpha_o[2][4];
#pragma unroll
      for (int qf = 0; qf < 2; ++qf)
#pragma unroll
        for (int r = 0; r < 4; ++r)
          alpha_o[qf][r] = __shfl(alpha_q[qf], asrc + r);
#pragma unroll
      for (int ms = 0; ms < 2; ++ms)
#pragma unroll
        for (int nt2 = 0; nt2 < 4; ++nt2)
#pragma unroll
          for (int r = 0; r < 4; ++r)
            Oacc[ms][nt2][r] *= alpha_o[ms][r];
    }
    // PV over this wave's 32-wide t-strip (A-frags in registers)
    {
      const int tcol = wt * 32 + quad * 8;
      __builtin_amdgcn_s_setprio(1);
#pragma unroll
      for (int nt2 = 0; nt2 < 4; ++nt2) {
        const f16x8 vf = *(const f16x8*)&Vt[(nt2 * 16 + lm) * kSV + tcol];
        Oacc[0][nt2] = __builtin_amdgcn_mfma_f32_16x16x32_f16(pfrag[0], vf, Oacc[0][nt2], 0, 0, 0);
        Oacc[1][nt2] = __builtin_amdgcn_mfma_f32_16x16x32_f16(pfrag[1], vf, Oacc[1][nt2], 0, 0, 0);
      }
      __builtin_amdgcn_s_setprio(0);
    }
  }
  // ---- merge the four t-strips per q-row (flash (m,l,O) merge) ----
  if (quad == 0) {
#pragma unroll
    for (int qf = 0; qf < 2; ++qf) {
      const int row = wq * 32 + qf * 16 + lm;
      mM[row][wt] = mrow[qf];
      lM[row][wt] = lrow[qf];
    }
  }
  __syncthreads();
  float fac[2][4], invL[2][4];
#pragma unroll
  for (int qf = 0; qf < 2; ++qf)
#pragma unroll
    for (int r = 0; r < 4; ++r) {
      const int row = wq * 32 + qf * 16 + quad * 4 + r;
      const float M = fmaxf(fmaxf(mM[row][0], mM[row][1]),
                            fmaxf(mM[row][2], mM[row][3]));
      const float L = lM[row][0] * exp2f(mM[row][0] - M)
                    + lM[row][1] * exp2f(mM[row][1] - M)
                    + lM[row][2] * exp2f(mM[row][2] - M)
                    + lM[row][3] * exp2f(mM[row][3] - M);
      fac[qf][r] = exp2f(mM[row][wt] - M);
      invL[qf][r] = 1.f / L;
    }
  float* OfA = (float*)Vt;   // 64 x 68 fp32 = 17408 B, exactly Vt's size
  float* OfB = (float*)Ks;   // 19008 B >= 17408 B
  if (!(wt & 1)) {
    float* Of = (wt == 0) ? OfA : OfB;
#pragma unroll
    for (int ms = 0; ms < 2; ++ms)
#pragma unroll
      for (int nt2 = 0; nt2 < 4; ++nt2)
#pragma unroll
        for (int r = 0; r < 4; ++r)
          Of[(wq * 32 + ms * 16 + quad * 4 + r) * 68 + nt2 * 16 + lm] =
              Oacc[ms][nt2][r] * fac[ms][r];
  }
  __syncthreads();
  if (wt & 1) {
    float* Of = (wt == 1) ? OfA : OfB;
#pragma unroll
    for (int ms = 0; ms < 2; ++ms)
#pragma unroll
      for (int nt2 = 0; nt2 < 4; ++nt2)
#pragma unroll
        for (int r = 0; r < 4; ++r)
          Of[(wq * 32 + ms * 16 + quad * 4 + r) * 68 + nt2 * 16 + lm] +=
              Oacc[ms][nt2][r] * fac[ms][r];
  }
  __syncthreads();
  if (wt == 0) {
#pragma unroll
    for (int ms = 0; ms < 2; ++ms)
#pragma unroll
      for (int r = 0; r < 4; ++r) {
        const int row = wq * 32 + ms * 16 + quad * 4 + r;
        const int q = q0 + row;
#pragma unroll
        for (int nt2 = 0; nt2 < 4; ++nt2) {
          const float o = (OfA[row * 68 + nt2 * 16 + lm]
                           + OfB[row * 68 + nt2 * 16 + lm]) * invL[ms][r];
          O[(size_t)(b * kS + q) * kE + h * kDH + nt2 * 16 + lm] = f2h(o);
        }
      }
  }
}

// ---------------- layernorm over E=512 (f16 in / f16 out) -------------------
// One row per WAVE: 64 lanes x 8 elems, shfl_xor butterfly, no LDS/barrier.
__global__ __launch_bounds__(256) void ln_kernel(const unsigned short* __restrict__ Xin,
        const float* __restrict__ w, const float* __restrict__ bb,
        unsigned short* __restrict__ Y) {
  const int wid = threadIdx.x >> 6, lane = threadIdx.x & 63;
  const int row = blockIdx.x * 4 + wid;
  const unsigned short* xr = Xin + (size_t)row * kE + lane * 8;
  const ushort4 a = *(const ushort4*)xr;
  const ushort4 c = *(const ushort4*)(xr + 4);
  float v[8] = { h2f(a.x), h2f(a.y), h2f(a.z), h2f(a.w),
                 h2f(c.x), h2f(c.y), h2f(c.z), h2f(c.w) };
  float s = 0.f, sq = 0.f;
#pragma unroll
  for (int j = 0; j < 8; ++j) { s += v[j]; sq += v[j] * v[j]; }
#pragma unroll
  for (int off = 32; off; off >>= 1) {
    s  += __shfl_xor(s, off);
    sq += __shfl_xor(sq, off);
  }
  const float mean = s * (1.f / kE);
  const float var  = sq * (1.f / kE) - mean * mean;
  const float rstd = rsqrtf(var + 1e-5f);
  const float4 w0 = *(const float4*)&w[lane * 8];
  const float4 w1 = *(const float4*)&w[lane * 8 + 4];
  const float4 b0 = *(const float4*)&bb[lane * 8];
  const float4 b1 = *(const float4*)&bb[lane * 8 + 4];
  const float wa[8] = { w0.x, w0.y, w0.z, w0.w, w1.x, w1.y, w1.z, w1.w };
  const float ba[8] = { b0.x, b0.y, b0.z, b0.w, b1.x, b1.y, b1.z, b1.w };
  ushort4 o0, o1;
  unsigned short* op = (unsigned short*)&o0;
#pragma unroll
  for (int j = 0; j < 4; ++j) op[j] = f2h((v[j] - mean) * rstd * wa[j] + ba[j]);
  op = (unsigned short*)&o1;
#pragma unroll
  for (int j = 0; j < 4; ++j) op[j] = f2h((v[4 + j] - mean) * rstd * wa[4 + j] + ba[4 + j]);
  unsigned short* yr = Y + (size_t)row * kE + lane * 8;
  *(ushort4*)yr = o0;
  *(ushort4*)(yr + 4) = o1;
}

// ---------------- final head: out[b,o] = sum_k x[b,k] W[k,o] + b[o] ---------
__global__ __launch_bounds__(256) void final_kernel(const unsigned short* __restrict__ X,
        const float* __restrict__ Wt, const float* __restrict__ bias,
        float* __restrict__ out) {
  const int b = blockIdx.y, chunk = blockIdx.x;
  const int tid = threadIdx.x;
  const unsigned short* xb = X + (size_t)b * (kS * kE);
  float acc[6] = {};
  const int k0 = chunk * 8192;                     // 128 chunks * 8192 = 1M
#pragma unroll 4
  for (int i = 0; i < 32; ++i) {
    const int kk = k0 + tid + i * 256;
    const float xv = h2f(xb[kk]);
    const float* wr = Wt + (size_t)kk * 6;
#pragma unroll
    for (int o = 0; o < 6; ++o) acc[o] = fmaf(xv, wr[o], acc[o]);
  }
#pragma unroll
  for (int o = 0; o < 6; ++o)
    for (int off = 32; off; off >>= 1) acc[o] += __shfl_down(acc[o], off);
  __shared__ float part[4][6];
  const int wid = tid >> 6;
  if ((tid & 63) == 0) {
#pragma unroll
    for (int o = 0; o < 6; ++o) part[wid][o] = acc[o];
  }
  __syncthreads();
  if (tid < 6) {
    float s2 = part[0][tid] + part[1][tid] + part[2][tid] + part[3][tid];
    if (chunk == 0) s2 += bias[tid];
    atomicAdd(&out[b * 6 + tid], s2);
  }
}

// ---------------------------------------------------------------------------
extern "C" void kernel_launch(void* const* d_in, const int* in_sizes, int n_in,
                              void* d_out, int out_size, void* d_ws, size_t ws_size,
                              hipStream_t stream) {
  (void)in_sizes; (void)n_in; (void)ws_size;
  const int*   tok   = (const int*)d_in[0];
  const float* emb   = (const float*)d_in[1];
  const float* ln_w  = (const float*)d_in[2];
  const float* ln_b  = (const float*)d_in[3];
  const float* q_w   = (const float*)d_in[4];
  const float* q_b   = (const float*)d_in[5];
  const float* k_w   = (const float*)d_in[6];
  const float* k_b   = (const float*)d_in[7];
  const float* v_w   = (const float*)d_in[8];
  const float* v_b   = (const float*)d_in[9];
  const float* fc1_w = (const float*)d_in[10];
  const float* fc1_b = (const float*)d_in[11];
  const float* fc2_w = (const float*)d_in[12];
  const float* fc2_b = (const float*)d_in[13];
  const float* out_w = (const float*)d_in[14];
  const float* out_b = (const float*)d_in[15];

  // workspace (float units): x16 | y16 | regA (qkvh f16 aliased by hbuf f16)
  // | f16 weights | qkv bias | VsT
  float* ws = (float*)d_ws;
  unsigned short* x16 = (unsigned short*)ws;                        // [4096][512]
  unsigned short* y16 = (unsigned short*)(ws + (size_t)kNX / 2);    // [4096][512]
  float* regA = ws + (size_t)kNX;
  unsigned short* qkvh = (unsigned short*)regA;                     // [4096][1536]
  unsigned short* hbuf = (unsigned short*)regA;                     // [4096][2048]
  unsigned short* wqkvT = (unsigned short*)(ws + (size_t)3 * kNX);  // [1536][512]
  unsigned short* fc1T  = wqkvT + (size_t)kQKV * kE;                // [2048][512]
  unsigned short* fc2T  = fc1T + (size_t)kHID * kE;                 // [512][2048]
  float* qkvb = (float*)(fc2T + (size_t)kE * kHID);                 // [1536]
  unsigned short* vsT = (unsigned short*)(qkvb + kQKV);             // [16][64][2048]

  // per-launch weight prep (graph-safe, no static guards)
  tcast_kernel<<<dim3(16, 16), 256, 0, stream>>>(q_w, wqkvT, kE, kE);
  tcast_kernel<<<dim3(16, 16), 256, 0, stream>>>(k_w, wqkvT + (size_t)kE * kE, kE, kE);
  tcast_kernel<<<dim3(16, 16), 256, 0, stream>>>(v_w, wqkvT + (size_t)2 * kE * kE, kE, kE);
  tcast_kernel<<<dim3(64, 16), 256, 0, stream>>>(fc1_w, fc1T, kE, kHID);
  tcast_kernel<<<dim3(16, 64), 256, 0, stream>>>(fc2_w, fc2T, kHID, kE);
  qkvb_kernel<<<dim3(6), 256, 0, stream>>>(q_b, k_b, v_b, qkvb);

  embed_kernel<<<dim3(kTok), 256, 0, stream>>>(tok, emb, x16);
  for (int l = 0; l < kL; ++l) {
    mfma_gemm<64, 0, 0><<<dim3(kQKV / 128, kTok / 64), 256, 0, stream>>>(
        x16, wqkvT, qkvb, nullptr, qkvh, kTok, kQKV, kE);
    vsumt_kernel<<<dim3(kS / 64, kH, kB), 256, 0, stream>>>(qkvh, vsT);
    flash_kernel<<<dim3(kS / 64, kH, kB), 512, 0, stream>>>(qkvh, vsT, y16);
    ln_kernel<<<dim3(kTok / 4), 256, 0, stream>>>(y16, ln_w, ln_b, x16);
    mfma_gemm<128, 1, 0><<<dim3(kHID / 128, kTok / 128), 256, 0, stream>>>(
        x16, fc1T, fc1_b, nullptr, hbuf, kTok, kHID, kE);
    mfma_gemm<64, 0, 1><<<dim3(kE / 128, kTok / 64), 256, 0, stream>>>(
        hbuf, fc2T, fc2_b, x16, y16, kTok, kE, kHID);
    ln_kernel<<<dim3(kTok / 4), 256, 0, stream>>>(y16, ln_w, ln_b, x16);
  }
  hipMemsetAsync(d_out, 0, (size_t)out_size * sizeof(float), stream);
  final_kernel<<<dim3(128, kB), 256, 0, stream>>>(x16, out_w, out_b, (float*)d_out);
}

// Round 10
// 1133.111 us; speedup vs baseline: 1.1636x; 1.1636x over previous
//
#include <hip/hip_runtime.h>
#include <math.h>

// ---------------------------------------------------------------------------
// LocalModel_76527727280750: 6-layer transformer w/ unfold-window attention.
// B=2 S=2048 E=512 H=8 DH=64 W=5 SK=2044 HID=2048 OUT=6 L=6, fp32 in/out.
//
// R17: recombination of measured wins.  R16's half-Q-hoist pushed flash
// over the 64-VGPR cliff (64->80 regs, occupancy 40->22%, 100.7->125.4us)
// -- REVERTED to the R15 flash (reads Q frags from LDS; VGPR=64 is flash's
// hard budget).  R16's BM=64 GEMM tiling (fc2 128->256 blocks, QKV
// 384->768; non-flash 583->566us) -- KEPT.  GEMM dbuf gload_lds staging
// (R15) unchanged.
// ---------------------------------------------------------------------------

namespace {
constexpr int kB   = 2;
constexpr int kS   = 2048;
constexpr int kE   = 512;
constexpr int kH   = 8;
constexpr int kDH  = 64;
constexpr int kSK  = 2044;   // S - W + 1
constexpr int kHID = 2048;
constexpr int kL   = 6;
constexpr float kScaleL2 = 0.125f * 1.44269504088896f;  // DH^-0.5 * log2(e)
constexpr int kTok = kB * kS;         // 4096 rows
constexpr int kNX  = kTok * kE;       // 2,097,152 floats
constexpr int kQKV = 3 * kE;          // 1536 fused row stride
constexpr int kSQ  = 72;              // Qs/Ks LDS row stride (f16), 144 B
constexpr int kSV  = 136;             // Vt LDS row stride (f16), 272 B
}

using f16x8   = __attribute__((ext_vector_type(8))) _Float16;
using floatx4 = __attribute__((ext_vector_type(4))) float;
using uint2v  = __attribute__((ext_vector_type(2))) unsigned int;
using uint4v  = __attribute__((ext_vector_type(4))) unsigned int;

static __device__ __forceinline__ unsigned short f2h(float f) {
  return __builtin_bit_cast(unsigned short, (_Float16)f);
}
static __device__ __forceinline__ float h2f(unsigned short u) {
  return (float)__builtin_bit_cast(_Float16, u);
}
static __device__ __forceinline__ unsigned int pk2h(float a, float b) {
  return __builtin_bit_cast(unsigned int, __builtin_amdgcn_cvt_pkrtz(a, b));
}
// direct global->LDS copy, 16 B per lane; lds base must be wave-uniform,
// HW writes at base + lane*16.
static __device__ __forceinline__ void gload_lds16(const unsigned short* g,
                                                   unsigned short* l) {
  __builtin_amdgcn_global_load_lds(
      (const __attribute__((address_space(1))) void*)g,
      (__attribute__((address_space(3))) void*)l, 16, 0, 0);
}
// partner value across the lane^16 split (rows 0<->1, 2<->3), VALU-only.
// even-row lanes: partner lands in new_vsrc (r[1]); odd-row: new_vdst (r[0]).
static __device__ __forceinline__ float red16(float x, bool hi) {
  const unsigned u = __builtin_bit_cast(unsigned, x);
  const uint2v r = __builtin_amdgcn_permlane16_swap(u, u, false, false);
  return __builtin_bit_cast(float, hi ? r[0] : r[1]);
}
// partner value across the lane^32 split (halves), VALU-only
static __device__ __forceinline__ float red32(float x, bool hi) {
  const unsigned u = __builtin_bit_cast(unsigned, x);
  const uint2v r = __builtin_amdgcn_permlane32_swap(u, u, false, false);
  return __builtin_bit_cast(float, hi ? r[0] : r[1]);
}

// ---------------- embedding + sinusoidal positional encoding (f16 out) ------
__global__ __launch_bounds__(256) void embed_kernel(const int* __restrict__ idx,
        const float* __restrict__ emb, unsigned short* __restrict__ X) {
  const int bs  = blockIdx.x;            // b*S + s
  const int s   = bs & (kS - 1);
  const int tok = idx[bs];
  const int t   = threadIdx.x;
#pragma unroll
  for (int r = 0; r < 2; ++r) {
    const int e = t + 256 * r;
    const int i = e >> 1;
    const float dv  = __expf((float)(2 * i) * (-9.210340371976184f / (float)kE));
    const float ang = (float)s * dv;
    const float pe  = (e & 1) ? cosf(ang) : sinf(ang);   // libm: accurate arg reduction
    X[bs * kE + e] = f2h(emb[tok * kE + e] + pe);
  }
}

// ---------------- weight transpose-cast: fp32 [K][N] -> f16 [N][K] ----------
__global__ __launch_bounds__(256) void tcast_kernel(const float* __restrict__ src,
        unsigned short* __restrict__ dst, int K, int N) {
  __shared__ float t[32][33];
  const int tid = threadIdx.x;
  const int tx = tid & 31, ty = tid >> 5;          // 32 x 8
  const int n0 = blockIdx.x * 32, k0 = blockIdx.y * 32;
#pragma unroll
  for (int p = 0; p < 4; ++p)
    t[ty + 8 * p][tx] = src[(size_t)(k0 + ty + 8 * p) * N + n0 + tx];
  __syncthreads();
#pragma unroll
  for (int p = 0; p < 4; ++p)
    dst[(size_t)(n0 + ty + 8 * p) * K + k0 + tx] = f2h(t[tx][ty + 8 * p]);
}

__global__ __launch_bounds__(256) void qkvb_kernel(const float* __restrict__ qb,
        const float* __restrict__ kb, const float* __restrict__ vb,
        float* __restrict__ dst) {
  const int i = blockIdx.x * 256 + threadIdx.x;    // grid 6 -> 1536
  dst[i] = (i < 512) ? qb[i] : ((i < 1024) ? kb[i - 512] : vb[i - 1024]);
}

// ---------------- f16 MFMA GEMM: C = act(A@B + bias [+ R]) ------------------
// A f16 [M,K], Bt f16 [N,K] (pre-transposed), C f16, R f16 residual.
// Tile BM x 128, 4 waves, K-step 32, double-buffered gload_lds staging
// (zero VGPR cost; ONE barrier per K-step, loads overlap the MFMA phase).
// BM=128: waves 2x2 quadrants of 64x64, acc[4][4].
// BM=64:  waves 1x4 strips of 64x32,  acc[4][2]  (tail-clean small grids).
template <int BM, int RELU, int RES>
__global__ __launch_bounds__(256) void mfma_gemm(const unsigned short* __restrict__ A,
        const unsigned short* __restrict__ Bt, const float* __restrict__ bias,
        const unsigned short* __restrict__ Rm, unsigned short* __restrict__ C,
        int M, int N, int K) {
  constexpr int NT = (BM == 128) ? 4 : 2;          // n-frags per wave
  constexpr int AP = BM / 64;                      // A staging passes
  __shared__ __align__(16) unsigned short As[2][BM * 32];
  __shared__ __align__(16) unsigned short Bs[2][128 * 32];
  const int tid = threadIdx.x;
  const int m0 = blockIdx.y * BM, n0 = blockIdx.x * 128;
  const int wid = tid >> 6, lane = tid & 63;
  const int lm = lane & 15, quad = lane >> 4;
  const int wm = (BM == 128) ? (wid & 1) * 64 : 0;
  const int wn = (BM == 128) ? (wid >> 1) * 64 : wid * 32;
  const int bn = tid >> 2, bk = (tid & 3) * 8;     // staging row / col
  const int wslot = wid * 512;                     // wave-uniform LDS slot
  // prologue: stage K-step 0 into buffer 0
#pragma unroll
  for (int p = 0; p < AP; ++p)
    gload_lds16(&A[(size_t)(m0 + bn + 64 * p) * K + bk], &As[0][p * 2048 + wslot]);
#pragma unroll
  for (int p = 0; p < 2; ++p)
    gload_lds16(&Bt[(size_t)(n0 + bn + 64 * p) * K + bk], &Bs[0][p * 2048 + wslot]);
  __syncthreads();                                 // vmcnt drain -> buf0 ready
  floatx4 acc[4][NT] = {};
  for (int k0 = 0; k0 < K; k0 += 32) {
    const int cur = (k0 >> 5) & 1;
    const int kn = k0 + 32;
    if (kn < K) {                                  // stage next tile (async)
#pragma unroll
      for (int p = 0; p < AP; ++p)
        gload_lds16(&A[(size_t)(m0 + bn + 64 * p) * K + kn + bk],
                    &As[cur ^ 1][p * 2048 + wslot]);
#pragma unroll
      for (int p = 0; p < 2; ++p)
        gload_lds16(&Bt[(size_t)(n0 + bn + 64 * p) * K + kn + bk],
                    &Bs[cur ^ 1][p * 2048 + wslot]);
    }
    f16x8 af[4], bf[NT];
#pragma unroll
    for (int t = 0; t < 4; ++t)
      af[t] = *(const f16x8*)&As[cur][(wm + t * 16 + lm) * 32 + quad * 8];
#pragma unroll
    for (int t = 0; t < NT; ++t)
      bf[t] = *(const f16x8*)&Bs[cur][(wn + t * 16 + lm) * 32 + quad * 8];
#pragma unroll
    for (int mt = 0; mt < 4; ++mt)
#pragma unroll
      for (int nt = 0; nt < NT; ++nt)
        acc[mt][nt] = __builtin_amdgcn_mfma_f32_16x16x32_f16(
            af[mt], bf[nt], acc[mt][nt], 0, 0, 0);
    __syncthreads();   // next buf ready (vmcnt) + all reads of cur done
  }
  // epilogue: D col = lane&15 (n), row = quad*4+reg (m)
#pragma unroll
  for (int mt = 0; mt < 4; ++mt) {
#pragma unroll
    for (int nt = 0; nt < NT; ++nt) {
      const int n = n0 + wn + nt * 16 + lm;
      const float bv = bias[n];
#pragma unroll
      for (int r = 0; r < 4; ++r) {
        const int m = m0 + wm + mt * 16 + quad * 4 + r;
        float o = acc[mt][nt][r] + bv;
        if (RES) o += h2f(Rm[(size_t)m * N + n]);
        if (RELU) o = fmaxf(o, 0.f);
        C[(size_t)m * N + n] = f2h(o);
      }
    }
  }
}

// ---------------- fused window-presum + transpose of V ----------------------
// VsT[(b*H+h)*64 + d][t] = sum_{w<5} V[b][t+w][h*64+d]  (f16, t-dim 2048,
// zero for t >= SK).  fp32 LDS tile stride 65 -> conflict-free col reads.
__global__ __launch_bounds__(256) void vsumt_kernel(const unsigned short* __restrict__ QKVh,
        unsigned short* __restrict__ VsT) {
  const int t0 = blockIdx.x * 64;                  // 32 t-tiles
  const int h = blockIdx.y, b = blockIdx.z;
  const int tid = threadIdx.x;
  __shared__ float Ls[68 * 65];
  for (int id = tid; id < 68 * 8; id += 256) {     // stage 68 rows x 64 d
    const int row = id >> 3, d8 = (id & 7) * 8;
    const int gt = t0 + row;
    float v[8];
    if (gt < kS) {
      const unsigned short* p =
          &QKVh[(size_t)(b * kS + gt) * kQKV + 2 * kE + h * kDH + d8];
      const ushort4 a = *(const ushort4*)p;
      const ushort4 c = *(const ushort4*)(p + 4);
      v[0] = h2f(a.x); v[1] = h2f(a.y); v[2] = h2f(a.z); v[3] = h2f(a.w);
      v[4] = h2f(c.x); v[5] = h2f(c.y); v[6] = h2f(c.z); v[7] = h2f(c.w);
    } else {
#pragma unroll
      for (int j = 0; j < 8; ++j) v[j] = 0.f;
    }
#pragma unroll
    for (int j = 0; j < 8; ++j) Ls[row * 65 + d8 + j] = v[j];
  }
  __syncthreads();
  const int t4 = (tid & 15) * 4;
#pragma unroll
  for (int c = 0; c < 4; ++c) {
    const int d = (tid >> 4) + 16 * c;
    ushort4 o;
    unsigned short* op = (unsigned short*)&o;
#pragma unroll
    for (int j = 0; j < 4; ++j) {
      const int tl = t4 + j;
      float s = Ls[(tl + 0) * 65 + d] + Ls[(tl + 1) * 65 + d]
              + Ls[(tl + 2) * 65 + d] + Ls[(tl + 3) * 65 + d]
              + Ls[(tl + 4) * 65 + d];
      if (t0 + tl >= kSK) s = 0.f;
      op[j] = f2h(s);
    }
    *(ushort4*)&VsT[((size_t)(b * kH + h) * kDH + d) * (size_t)kS + t0 + t4] = o;
  }
}

// ---------------- MFMA flash attention (unfold contraction) -----------------
// Block = 512 thr (8 waves 2x4), (qt of 64 q, h, b), grid 512.
// Wave (wq,wt): q-rows 32wq..+32 x t-strip 32wt..+32 of each 128-wide tile.
// QK^T computed SWAPPED: sac[tf][qf] = mfma(K,Q) -> D row = t (quad*4+r),
// col = q (lm).  Softmax reduce over t is in-lane + permlane16/32 swaps.
// PV A-frags built IN REGISTERS from e via cvt_pkrtz + permlane swaps.
// T13 defer-max: when __all(max growth <= 8) keep stale m (alpha==1) and
// skip the Oacc rescale + alpha bpermutes.  4 strips merged at kernel end.
// VGPR budget is EXACTLY 64 (the occupancy cliff) -- no reg-costing edits.
__global__ __launch_bounds__(512) void flash_kernel(const unsigned short* __restrict__ QKVh,
        const unsigned short* __restrict__ VsT, unsigned short* __restrict__ O) {
  const int tid = threadIdx.x;
  const int qt = blockIdx.x, h = blockIdx.y, b = blockIdx.z;
  const int q0 = qt * 64;
  const int wid = tid >> 6, lane = tid & 63;
  const int lm = lane & 15, quad = lane >> 4;
  const bool h16 = (lane & 16) != 0, h32 = (lane & 32) != 0;
  const int wq = wid >> 2, wt = wid & 3;
  const int bh = b * kH + h;

  __shared__ __align__(16) unsigned short Qs[68 * kSQ];    //  9.8 KB
  __shared__ __align__(16) unsigned short Ks[132 * kSQ];   // 19.0 KB
  __shared__ __align__(16) unsigned short Vt[64 * kSV];    // 17.4 KB  [d][t]
  __shared__ float mM[64][4], lM[64][4];

  // Q staging: rows i -> global q0-2+i (zero-pad OOB)
  for (int id = tid; id < 68 * 16; id += 512) {
    const int row = id >> 4, c4 = (id & 15) * 4;
    const int gq = q0 - 2 + row;
    ushort4 v = make_ushort4(0, 0, 0, 0);
    if (gq >= 0 && gq < kS)
      v = *(const ushort4*)&QKVh[(size_t)(b * kS + gq) * kQKV + h * kDH + c4];
    *(ushort4*)&Qs[row * kSQ + c4] = v;
  }

  // register-prefetch staging (fixed per-thread mapping; 512 threads)
  const int prow = tid >> 4;                 // 0..31
  const int pc4 = (tid & 15) * 4, pc8 = (tid & 15) * 8;
  ushort4 kreg[5];
  uint4 vreg[2];
#define PREFETCH(T0)                                                          \
  {                                                                           \
    _Pragma("unroll")                                                         \
    for (int p = 0; p < 5; ++p) {                                             \
      const int row = prow + 32 * p;                                          \
      ushort4 v = make_ushort4(0, 0, 0, 0);                                   \
      if (row < 132) {                                                        \
        const int gk = (T0) + row;                                            \
        if (gk < kS)                                                          \
          v = *(const ushort4*)&QKVh[(size_t)(b * kS + gk) * kQKV + kE +      \
                                     h * kDH + pc4];                          \
      }                                                                       \
      kreg[p] = v;                                                            \
    }                                                                         \
    _Pragma("unroll")                                                         \
    for (int p = 0; p < 2; ++p)                                               \
      vreg[p] = *(const uint4*)&VsT[((size_t)bh * kDH + prow + 32 * p) *      \
                                    (size_t)kS + (T0) + pc8];                 \
  }
  PREFETCH(0)

  float mrow[2], lrow[2];                    // per qf, q = wq*32+qf*16+lm,
  mrow[0] = mrow[1] = -1e30f;                // replicated across quads
  lrow[0] = lrow[1] = 0.f;
  floatx4 Oacc[2][4] = {};   // [qf][nt2]: row wq*32+qf*16+quad*4+r, col nt2*16+lm
  const int asrc = (lane >> 2) & 12;         // = quad*4 (shfl src base)

  for (int t0 = 0; t0 < kSK; t0 += 128) {          // 16 iterations
    __syncthreads();                                // prev iter LDS reads done
#pragma unroll
    for (int p = 0; p < 5; ++p) {                   // write prefetched K tile
      const int row = prow + 32 * p;
      if (row < 132) *(ushort4*)&Ks[row * kSQ + pc4] = kreg[p];
    }
#pragma unroll
    for (int p = 0; p < 2; ++p)                     // write prefetched Vt tile
      *(uint4*)&Vt[(prow + 32 * p) * kSV + pc8] = vreg[p];
    __syncthreads();
    const int tn = t0 + 128;
    if (tn < kSK) PREFETCH(tn)                      // next tile in flight

    // QK^T swapped: 10 k-steps (w = kk>>1, d0 = (kk&1)*32)
    // sac[tf][qf]: row = t (wt*32+tf*16+quad*4+r), col = q (wq*32+qf*16+lm)
    floatx4 sac[2][2] = {};
    __builtin_amdgcn_s_setprio(1);
#pragma unroll
    for (int kk = 0; kk < 10; ++kk) {
      const int w = kk >> 1, d0 = (kk & 1) * 32;
      const f16x8 kf0 = *(const f16x8*)&Ks[(wt * 32 + lm + w) * kSQ + d0 + quad * 8];
      const f16x8 kf1 = *(const f16x8*)&Ks[(wt * 32 + 16 + lm + w) * kSQ + d0 + quad * 8];
      const f16x8 qf0 = *(const f16x8*)&Qs[(wq * 32 + lm + w) * kSQ + d0 + quad * 8];
      const f16x8 qf1 = *(const f16x8*)&Qs[(wq * 32 + 16 + lm + w) * kSQ + d0 + quad * 8];
      sac[0][0] = __builtin_amdgcn_mfma_f32_16x16x32_f16(kf0, qf0, sac[0][0], 0, 0, 0);
      sac[0][1] = __builtin_amdgcn_mfma_f32_16x16x32_f16(kf0, qf1, sac[0][1], 0, 0, 0);
      sac[1][0] = __builtin_amdgcn_mfma_f32_16x16x32_f16(kf1, qf0, sac[1][0], 0, 0, 0);
      sac[1][1] = __builtin_amdgcn_mfma_f32_16x16x32_f16(kf1, qf1, sac[1][1], 0, 0, 0);
    }
    __builtin_amdgcn_s_setprio(0);

    // OOB t masking: wave-uniform branch, taken by one wave on the last tile
    if (t0 + wt * 32 + 32 > kSK) {
#pragma unroll
      for (int tf = 0; tf < 2; ++tf)
#pragma unroll
        for (int r = 0; r < 4; ++r) {
          const int tg = t0 + wt * 32 + tf * 16 + quad * 4 + r;
          if (tg >= kSK) { sac[tf][0][r] = -1e30f; sac[tf][1][r] = -1e30f; }
        }
    }

    // softmax: reduce over t = in-lane (2 tf x 4 r) + permlane 16/32 swaps
    float alpha_q[2];
    int skip_q[2];
    f16x8 pfrag[2];
#pragma unroll
    for (int qf = 0; qf < 2; ++qf) {
      float mx = fmaxf(
          fmaxf(fmaxf(sac[0][qf][0], sac[0][qf][1]), fmaxf(sac[0][qf][2], sac[0][qf][3])),
          fmaxf(fmaxf(sac[1][qf][0], sac[1][qf][1]), fmaxf(sac[1][qf][2], sac[1][qf][3])));
      mx = fmaxf(mx, red16(mx, h16));
      mx = fmaxf(mx, red32(mx, h32));
      const float mxs = mx * kScaleL2;
      // T13 defer-max: keep stale m when growth <= 8 (P bounded by 2^8)
      const int skip = __all(mxs <= mrow[qf] + 8.f);
      float mnew, al;
      if (skip) { mnew = mrow[qf]; al = 1.f; }
      else      { mnew = fmaxf(mrow[qf], mxs); al = exp2f(mrow[qf] - mnew); }
      float e[2][4];
#pragma unroll
      for (int tf = 0; tf < 2; ++tf)
#pragma unroll
        for (int r = 0; r < 4; ++r)
          e[tf][r] = exp2f(fmaf(sac[tf][qf][r], kScaleL2, -mnew));
      float ps = ((e[0][0] + e[0][1]) + (e[0][2] + e[0][3]))
               + ((e[1][0] + e[1][1]) + (e[1][2] + e[1][3]));
      ps += red16(ps, h16);
      ps += red32(ps, h32);
      lrow[qf] = lrow[qf] * al + ps;
      mrow[qf] = mnew;
      alpha_q[qf] = al;
      skip_q[qf] = skip;
      // build PV A-frag in registers: words w[tf][p] = (e[tf][2p], e[tf][2p+1])
      // dest dword dw covers t = quad*8 + 2dw + {0,1}
      const unsigned w00 = pk2h(e[0][0], e[0][1]);
      const unsigned w01 = pk2h(e[0][2], e[0][3]);
      const unsigned w10 = pk2h(e[1][0], e[1][1]);
      const unsigned w11 = pk2h(e[1][2], e[1][3]);
      // X=[w00r0,w00r1,w10r0,w10r1], Y=[w00r2,w00r3,w10r2,w10r3] (by 16-row)
      const uint2v sA = __builtin_amdgcn_permlane32_swap(w00, w10, false, false);
      const uint2v dA = __builtin_amdgcn_permlane16_swap(sA[0], sA[1], false, false); // {dw0, dw2}
      const uint2v sB = __builtin_amdgcn_permlane32_swap(w01, w11, false, false);
      const uint2v dB = __builtin_amdgcn_permlane16_swap(sB[0], sB[1], false, false); // {dw1, dw3}
      uint4v fr;
      fr[0] = dA[0]; fr[1] = dB[0]; fr[2] = dA[1]; fr[3] = dB[1];
      pfrag[qf] = __builtin_bit_cast(f16x8, fr);
    }
    // rescale Oacc only when some max actually grew (wave-uniform branch)
    if (!(skip_q[0] && skip_q[1])) {
      float alpha_o[2][4];
#pragma unroll
      for (int qf = 0; qf < 2; ++qf)
#pragma unroll
        for (int r = 0; r < 4; ++r)
          alpha_o[qf][r] = __shfl(alpha_q[qf], asrc + r);
#pragma unroll
      for (int ms = 0; ms < 2; ++ms)
#pragma unroll
        for (int nt2 = 0; nt2 < 4; ++nt2)
#pragma unroll
          for (int r = 0; r < 4; ++r)
            Oacc[ms][nt2][r] *= alpha_o[ms][r];
    }
    // PV over this wave's 32-wide t-strip (A-frags in registers)
    {
      const int tcol = wt * 32 + quad * 8;
      __builtin_amdgcn_s_setprio(1);
#pragma unroll
      for (int nt2 = 0; nt2 < 4; ++nt2) {
        const f16x8 vf = *(const f16x8*)&Vt[(nt2 * 16 + lm) * kSV + tcol];
        Oacc[0][nt2] = __builtin_amdgcn_mfma_f32_16x16x32_f16(pfrag[0], vf, Oacc[0][nt2], 0, 0, 0);
        Oacc[1][nt2] = __builtin_amdgcn_mfma_f32_16x16x32_f16(pfrag[1], vf, Oacc[1][nt2], 0, 0, 0);
      }
      __builtin_amdgcn_s_setprio(0);
    }
  }
  // ---- merge the four t-strips per q-row (flash (m,l,O) merge) ----
  if (quad == 0) {
#pragma unroll
    for (int qf = 0; qf < 2; ++qf) {
      const int row = wq * 32 + qf * 16 + lm;
      mM[row][wt] = mrow[qf];
      lM[row][wt] = lrow[qf];
    }
  }
  __syncthreads();
  float fac[2][4], invL[2][4];
#pragma unroll
  for (int qf = 0; qf < 2; ++qf)
#pragma unroll
    for (int r = 0; r < 4; ++r) {
      const int row = wq * 32 + qf * 16 + quad * 4 + r;
      const float M = fmaxf(fmaxf(mM[row][0], mM[row][1]),
                            fmaxf(mM[row][2], mM[row][3]));
      const float L = lM[row][0] * exp2f(mM[row][0] - M)
                    + lM[row][1] * exp2f(mM[row][1] - M)
                    + lM[row][2] * exp2f(mM[row][2] - M)
                    + lM[row][3] * exp2f(mM[row][3] - M);
      fac[qf][r] = exp2f(mM[row][wt] - M);
      invL[qf][r] = 1.f / L;
    }
  float* OfA = (float*)Vt;   // 64 x 68 fp32 = 17408 B, exactly Vt's size
  float* OfB = (float*)Ks;   // 19008 B >= 17408 B
  if (!(wt & 1)) {
    float* Of = (wt == 0) ? OfA : OfB;
#pragma unroll
    for (int ms = 0; ms < 2; ++ms)
#pragma unroll
      for (int nt2 = 0; nt2 < 4; ++nt2)
#pragma unroll
        for (int r = 0; r < 4; ++r)
          Of[(wq * 32 + ms * 16 + quad * 4 + r) * 68 + nt2 * 16 + lm] =
              Oacc[ms][nt2][r] * fac[ms][r];
  }
  __syncthreads();
  if (wt & 1) {
    float* Of = (wt == 1) ? OfA : OfB;
#pragma unroll
    for (int ms = 0; ms < 2; ++ms)
#pragma unroll
      for (int nt2 = 0; nt2 < 4; ++nt2)
#pragma unroll
        for (int r = 0; r < 4; ++r)
          Of[(wq * 32 + ms * 16 + quad * 4 + r) * 68 + nt2 * 16 + lm] +=
              Oacc[ms][nt2][r] * fac[ms][r];
  }
  __syncthreads();
  if (wt == 0) {
#pragma unroll
    for (int ms = 0; ms < 2; ++ms)
#pragma unroll
      for (int r = 0; r < 4; ++r) {
        const int row = wq * 32 + ms * 16 + quad * 4 + r;
        const int q = q0 + row;
#pragma unroll
        for (int nt2 = 0; nt2 < 4; ++nt2) {
          const float o = (OfA[row * 68 + nt2 * 16 + lm]
                           + OfB[row * 68 + nt2 * 16 + lm]) * invL[ms][r];
          O[(size_t)(b * kS + q) * kE + h * kDH + nt2 * 16 + lm] = f2h(o);
        }
      }
  }
}

// ---------------- layernorm over E=512 (f16 in / f16 out) -------------------
// One row per WAVE: 64 lanes x 8 elems, shfl_xor butterfly, no LDS/barrier.
__global__ __launch_bounds__(256) void ln_kernel(const unsigned short* __restrict__ Xin,
        const float* __restrict__ w, const float* __restrict__ bb,
        unsigned short* __restrict__ Y) {
  const int wid = threadIdx.x >> 6, lane = threadIdx.x & 63;
  const int row = blockIdx.x * 4 + wid;
  const unsigned short* xr = Xin + (size_t)row * kE + lane * 8;
  const ushort4 a = *(const ushort4*)xr;
  const ushort4 c = *(const ushort4*)(xr + 4);
  float v[8] = { h2f(a.x), h2f(a.y), h2f(a.z), h2f(a.w),
                 h2f(c.x), h2f(c.y), h2f(c.z), h2f(c.w) };
  float s = 0.f, sq = 0.f;
#pragma unroll
  for (int j = 0; j < 8; ++j) { s += v[j]; sq += v[j] * v[j]; }
#pragma unroll
  for (int off = 32; off; off >>= 1) {
    s  += __shfl_xor(s, off);
    sq += __shfl_xor(sq, off);
  }
  const float mean = s * (1.f / kE);
  const float var  = sq * (1.f / kE) - mean * mean;
  const float rstd = rsqrtf(var + 1e-5f);
  const float4 w0 = *(const float4*)&w[lane * 8];
  const float4 w1 = *(const float4*)&w[lane * 8 + 4];
  const float4 b0 = *(const float4*)&bb[lane * 8];
  const float4 b1 = *(const float4*)&bb[lane * 8 + 4];
  const float wa[8] = { w0.x, w0.y, w0.z, w0.w, w1.x, w1.y, w1.z, w1.w };
  const float ba[8] = { b0.x, b0.y, b0.z, b0.w, b1.x, b1.y, b1.z, b1.w };
  ushort4 o0, o1;
  unsigned short* op = (unsigned short*)&o0;
#pragma unroll
  for (int j = 0; j < 4; ++j) op[j] = f2h((v[j] - mean) * rstd * wa[j] + ba[j]);
  op = (unsigned short*)&o1;
#pragma unroll
  for (int j = 0; j < 4; ++j) op[j] = f2h((v[4 + j] - mean) * rstd * wa[4 + j] + ba[4 + j]);
  unsigned short* yr = Y + (size_t)row * kE + lane * 8;
  *(ushort4*)yr = o0;
  *(ushort4*)(yr + 4) = o1;
}

// ---------------- final head: out[b,o] = sum_k x[b,k] W[k,o] + b[o] ---------
__global__ __launch_bounds__(256) void final_kernel(const unsigned short* __restrict__ X,
        const float* __restrict__ Wt, const float* __restrict__ bias,
        float* __restrict__ out) {
  const int b = blockIdx.y, chunk = blockIdx.x;
  const int tid = threadIdx.x;
  const unsigned short* xb = X + (size_t)b * (kS * kE);
  float acc[6] = {};
  const int k0 = chunk * 8192;                     // 128 chunks * 8192 = 1M
#pragma unroll 4
  for (int i = 0; i < 32; ++i) {
    const int kk = k0 + tid + i * 256;
    const float xv = h2f(xb[kk]);
    const float* wr = Wt + (size_t)kk * 6;
#pragma unroll
    for (int o = 0; o < 6; ++o) acc[o] = fmaf(xv, wr[o], acc[o]);
  }
#pragma unroll
  for (int o = 0; o < 6; ++o)
    for (int off = 32; off; off >>= 1) acc[o] += __shfl_down(acc[o], off);
  __shared__ float part[4][6];
  const int wid = tid >> 6;
  if ((tid & 63) == 0) {
#pragma unroll
    for (int o = 0; o < 6; ++o) part[wid][o] = acc[o];
  }
  __syncthreads();
  if (tid < 6) {
    float s2 = part[0][tid] + part[1][tid] + part[2][tid] + part[3][tid];
    if (chunk == 0) s2 += bias[tid];
    atomicAdd(&out[b * 6 + tid], s2);
  }
}

// ---------------------------------------------------------------------------
extern "C" void kernel_launch(void* const* d_in, const int* in_sizes, int n_in,
                              void* d_out, int out_size, void* d_ws, size_t ws_size,
                              hipStream_t stream) {
  (void)in_sizes; (void)n_in; (void)ws_size;
  const int*   tok   = (const int*)d_in[0];
  const float* emb   = (const float*)d_in[1];
  const float* ln_w  = (const float*)d_in[2];
  const float* ln_b  = (const float*)d_in[3];
  const float* q_w   = (const float*)d_in[4];
  const float* q_b   = (const float*)d_in[5];
  const float* k_w   = (const float*)d_in[6];
  const float* k_b   = (const float*)d_in[7];
  const float* v_w   = (const float*)d_in[8];
  const float* v_b   = (const float*)d_in[9];
  const float* fc1_w = (const float*)d_in[10];
  const float* fc1_b = (const float*)d_in[11];
  const float* fc2_w = (const float*)d_in[12];
  const float* fc2_b = (const float*)d_in[13];
  const float* out_w = (const float*)d_in[14];
  const float* out_b = (const float*)d_in[15];

  // workspace (float units): x16 | y16 | regA (qkvh f16 aliased by hbuf f16)
  // | f16 weights | qkv bias | VsT
  float* ws = (float*)d_ws;
  unsigned short* x16 = (unsigned short*)ws;                        // [4096][512]
  unsigned short* y16 = (unsigned short*)(ws + (size_t)kNX / 2);    // [4096][512]
  float* regA = ws + (size_t)kNX;
  unsigned short* qkvh = (unsigned short*)regA;                     // [4096][1536]
  unsigned short* hbuf = (unsigned short*)regA;                     // [4096][2048]
  unsigned short* wqkvT = (unsigned short*)(ws + (size_t)3 * kNX);  // [1536][512]
  unsigned short* fc1T  = wqkvT + (size_t)kQKV * kE;                // [2048][512]
  unsigned short* fc2T  = fc1T + (size_t)kHID * kE;                 // [512][2048]
  float* qkvb = (float*)(fc2T + (size_t)kE * kHID);                 // [1536]
  unsigned short* vsT = (unsigned short*)(qkvb + kQKV);             // [16][64][2048]

  // per-launch weight prep (graph-safe, no static guards)
  tcast_kernel<<<dim3(16, 16), 256, 0, stream>>>(q_w, wqkvT, kE, kE);
  tcast_kernel<<<dim3(16, 16), 256, 0, stream>>>(k_w, wqkvT + (size_t)kE * kE, kE, kE);
  tcast_kernel<<<dim3(16, 16), 256, 0, stream>>>(v_w, wqkvT + (size_t)2 * kE * kE, kE, kE);
  tcast_kernel<<<dim3(64, 16), 256, 0, stream>>>(fc1_w, fc1T, kE, kHID);
  tcast_kernel<<<dim3(16, 64), 256, 0, stream>>>(fc2_w, fc2T, kHID, kE);
  qkvb_kernel<<<dim3(6), 256, 0, stream>>>(q_b, k_b, v_b, qkvb);

  embed_kernel<<<dim3(kTok), 256, 0, stream>>>(tok, emb, x16);
  for (int l = 0; l < kL; ++l) {
    mfma_gemm<64, 0, 0><<<dim3(kQKV / 128, kTok / 64), 256, 0, stream>>>(
        x16, wqkvT, qkvb, nullptr, qkvh, kTok, kQKV, kE);
    vsumt_kernel<<<dim3(kS / 64, kH, kB), 256, 0, stream>>>(qkvh, vsT);
    flash_kernel<<<dim3(kS / 64, kH, kB), 512, 0, stream>>>(qkvh, vsT, y16);
    ln_kernel<<<dim3(kTok / 4), 256, 0, stream>>>(y16, ln_w, ln_b, x16);
    mfma_gemm<128, 1, 0><<<dim3(kHID / 128, kTok / 128), 256, 0, stream>>>(
        x16, fc1T, fc1_b, nullptr, hbuf, kTok, kHID, kE);
    mfma_gemm<64, 0, 1><<<dim3(kE / 128, kTok / 64), 256, 0, stream>>>(
        hbuf, fc2T, fc2_b, x16, y16, kTok, kE, kHID);
    ln_kernel<<<dim3(kTok / 4), 256, 0, stream>>>(y16, ln_w, ln_b, x16);
  }
  hipMemsetAsync(d_out, 0, (size_t)out_size * sizeof(float), stream);
  final_kernel<<<dim3(128, kB), 256, 0, stream>>>(x16, out_w, out_b, (float*)d_out);
}